// Round 6
// baseline (834.549 us; speedup 1.0000x reference)
//
#include <hip/hip_runtime.h>
#include <cmath>

#define Nn 20000
#define Ee 320000
#define Bb 64

typedef unsigned short u16;
typedef __bf16 bf16x8 __attribute__((ext_vector_type(8)));
typedef float f32x4 __attribute__((ext_vector_type(4)));

// ---------------- workspace layout (float units) ----------------
static const size_t OUT0 = 0;                    // N*512 fp32
static const size_t XL0B = 10240000;             // N*512 bf16 (layer1 reuses as N*256)
static const size_t XR0B = 15360000;             // N*512 bf16
static const size_t H0B  = 20480000;             // N*512 bf16 (post-BN h0)
static const size_t XB   = 25600000;             // N*256 bf16
static const size_t WTS  = 28160000;             // 4 x 131072 u16 (transposed bf16 weights)
static const size_t OUT1 = 28422144;             // N*64 fp32
static const size_t ESC  = 29702144;             // E*4 fp32
static const size_t CSRI = 30982144;             // ints: offs[N+1], cursor[N], eidx[E], goffs[B+1]
static const size_t SMALL= 31342272;
static const size_t BN0S = SMALL;                // 1024
static const size_t BN1S = BN0S + 1024;          // 128
static const size_t ZCNT = 1152;                 // floats to zero (BN stats only)
static const size_t EMB  = BN1S + 128;           // 64*64 emb
static const size_t W1TF = EMB + 4096;           // 256*64 fp32 W1 transposed
static const size_t W2TF = W1TF + 16384;         // 128*256 fp32 W2 transposed

__device__ __forceinline__ float lrelu(float x){ return x > 0.f ? x : 0.2f * x; }
__device__ __forceinline__ float elu(float x){ return x > 0.f ? x : expm1f(x); }
__device__ __forceinline__ u16 fbf(float f){           // fp32 -> bf16 RNE
  unsigned u = __float_as_uint(f);
  return (u16)((u + 0x7fffu + ((u >> 16) & 1u)) >> 16);
}
__device__ __forceinline__ float blo(unsigned u){ return __uint_as_float(u << 16); }
__device__ __forceinline__ float bhi(unsigned u){ return __uint_as_float(u & 0xffff0000u); }
__device__ __forceinline__ float b2f(u16 v){ return __uint_as_float(((unsigned)v) << 16); }

// ---------------- fp32 -> bf16 (n multiple of 4) ----------------
__global__ __launch_bounds__(256) void conv_bf(const float* __restrict__ src,
                                               u16* __restrict__ dst, int n4){
  int i = blockIdx.x * 256 + threadIdx.x;
  if (i < n4){
    float4 v = ((const float4*)src)[i];
    ushort4 o; o.x = fbf(v.x); o.y = fbf(v.y); o.z = fbf(v.z); o.w = fbf(v.w);
    ((ushort4*)dst)[i] = o;
  }
}

// ---------------- W[K][N] fp32 -> WT[N][K] bf16 ----------------
__global__ __launch_bounds__(256) void conv_wt(const float* __restrict__ W,
                                               u16* __restrict__ WT, int K, int N){
  int i = blockIdx.x * 256 + threadIdx.x;
  if (i < K * N){
    int n = i / K, k = i - n * K;
    WT[i] = fbf(W[k * N + n]);
  }
}

// ---------------- W[K][N] fp32 -> WT[N][K] fp32 (classifier weights) ----------------
__global__ __launch_bounds__(256) void conv_wtf(const float* __restrict__ W,
                                                float* __restrict__ WT, int K, int N){
  int i = blockIdx.x * 256 + threadIdx.x;
  if (i < K * N){
    int n = i / K, k = i - n * K;
    WT[i] = W[k * N + n];
  }
}

// ---------------- MFMA GEMM: O[M][Nc] = A[M][K] @ WT[Nc][K]^T, all bf16, fp32 acc
__global__ __launch_bounds__(256) void gemm_mfma(const u16* __restrict__ A,
    const u16* __restrict__ WTa, const u16* __restrict__ WTb,
    u16* __restrict__ Oa, u16* __restrict__ Ob, int M, int K, int Nc){
  const u16* WT = blockIdx.z ? WTb : WTa;
  u16* O = blockIdx.z ? Ob : Oa;
  __shared__ u16 As[128 * 40];   // row stride 40 u16 = 80B -> 2-way bank alias (free)
  __shared__ u16 Bs[128 * 40];
  int tid = threadIdx.x;
  int m0 = blockIdx.y * 128, n0 = blockIdx.x * 128;
  int lane = tid & 63, w = tid >> 6;
  int wr = (w >> 1) * 64, wc = (w & 1) * 64;
  int l16 = lane & 15, kq = lane >> 4;
  f32x4 acc[4][4] = {};
  int srow = tid >> 2, scol = (tid & 3) * 8;
  for (int kt = 0; kt < K; kt += 32){
    #pragma unroll
    for (int r = 0; r < 2; r++){
      int row = r * 64 + srow;
      uint4 av = make_uint4(0u, 0u, 0u, 0u);
      int gr = m0 + row;
      if (gr < M) av = *(const uint4*)&A[(size_t)gr * K + kt + scol];
      *(uint4*)&As[row * 40 + scol] = av;
      uint4 bv = *(const uint4*)&WT[(size_t)(n0 + row) * K + kt + scol];
      *(uint4*)&Bs[row * 40 + scol] = bv;
    }
    __syncthreads();
    bf16x8 af[4], bfr[4];
    #pragma unroll
    for (int i = 0; i < 4; i++){
      af[i]  = *(bf16x8*)&As[(wr + i * 16 + l16) * 40 + kq * 8];
      bfr[i] = *(bf16x8*)&Bs[(wc + i * 16 + l16) * 40 + kq * 8];
    }
    #pragma unroll
    for (int i = 0; i < 4; i++)
      #pragma unroll
      for (int j = 0; j < 4; j++)
        acc[i][j] = __builtin_amdgcn_mfma_f32_16x16x32_bf16(af[i], bfr[j], acc[i][j], 0, 0, 0);
    __syncthreads();
  }
  #pragma unroll
  for (int i = 0; i < 4; i++){
    #pragma unroll
    for (int rg = 0; rg < 4; rg++){
      int row = m0 + wr + i * 16 + kq * 4 + rg;
      if (row < M){
        #pragma unroll
        for (int j = 0; j < 4; j++){
          int col = n0 + wc + j * 16 + l16;
          O[(size_t)row * Nc + col] = fbf(acc[i][j][rg]);
        }
      }
    }
  }
}

// ---------------- CSR build ----------------
__global__ __launch_bounds__(256) void csr_hist(const int* __restrict__ ei,
                                                int* __restrict__ cursor){
  int e = blockIdx.x * 256 + threadIdx.x;
  if (e < Ee) atomicAdd(&cursor[ei[Ee + e]], 1);
}

__global__ __launch_bounds__(1024) void csr_scan(int* __restrict__ offs,
                                                 int* __restrict__ cursor){
  __shared__ int part[1024];
  int t = threadIdx.x;
  int base = t * 20;
  int loc[20];
  int s = 0;
  #pragma unroll
  for (int i = 0; i < 20; i++){
    int idx = base + i;
    int v = (idx < Nn) ? cursor[idx] : 0;
    loc[i] = s; s += v;
  }
  part[t] = s;
  __syncthreads();
  for (int off = 1; off < 1024; off <<= 1){
    int v = 0;
    if (t >= off) v = part[t - off];
    __syncthreads();
    if (t >= off) part[t] += v;
    __syncthreads();
  }
  int pre = (t == 0) ? 0 : part[t - 1];
  #pragma unroll
  for (int i = 0; i < 20; i++){
    int idx = base + i;
    if (idx < Nn){ offs[idx] = pre + loc[i]; cursor[idx] = pre + loc[i]; }
  }
  if (t == 1023) offs[Nn] = part[1023];
}

__global__ __launch_bounds__(256) void csr_fill(const int* __restrict__ ei,
    int* __restrict__ cursor, int* __restrict__ eidx){
  int e = blockIdx.x * 256 + threadIdx.x;
  if (e < Ee){
    int d = ei[Ee + e];
    int p = atomicAdd(&cursor[d], 1);
    eidx[p] = e;
  }
}

// ---------------- graph boundaries from sorted batch
__global__ __launch_bounds__(256) void graph_bounds(const int* __restrict__ batch,
                                                    int* __restrict__ goffs){
  int i = blockIdx.x * 256 + threadIdx.x;
  if (i >= Nn) return;
  int b1 = batch[i];
  int b0 = (i == 0) ? -1 : batch[i - 1];
  for (int b = b0 + 1; b <= b1; b++) goffs[b] = i;
  if (i == Nn - 1)
    for (int b = b1 + 1; b <= Bb; b++) goffs[b] = Nn;
}

// ---------------- layer-0 edge scores (bf16 xl/xr, 512 ch), wave/edge
__global__ __launch_bounds__(256) void score_l0(const u16* __restrict__ xl,
    const u16* __restrict__ xr, const float* __restrict__ ea,
    const float* __restrict__ we, const float* __restrict__ att,
    const int* __restrict__ ei, float* __restrict__ esc){
  int eid = blockIdx.x * 4 + (threadIdx.x >> 6);
  int lane = threadIdx.x & 63;
  int src = ei[eid], dst = ei[Ee + eid];
  float a = ea[eid];
  int c = lane << 3;
  uint4 lu = *(const uint4*)&xl[(size_t)src * 512 + c];
  uint4 ru = *(const uint4*)&xr[(size_t)dst * 512 + c];
  float4 w0 = *(const float4*)&we[c],  w1 = *(const float4*)&we[c + 4];
  float4 t0 = *(const float4*)&att[c], t1 = *(const float4*)&att[c + 4];
  float p = 0.f;
  p += lrelu(blo(lu.x) + blo(ru.x) + a * w0.x) * t0.x;
  p += lrelu(bhi(lu.x) + bhi(ru.x) + a * w0.y) * t0.y;
  p += lrelu(blo(lu.y) + blo(ru.y) + a * w0.z) * t0.z;
  p += lrelu(bhi(lu.y) + bhi(ru.y) + a * w0.w) * t0.w;
  p += lrelu(blo(lu.z) + blo(ru.z) + a * w1.x) * t1.x;
  p += lrelu(bhi(lu.z) + bhi(ru.z) + a * w1.y) * t1.y;
  p += lrelu(blo(lu.w) + blo(ru.w) + a * w1.z) * t1.z;
  p += lrelu(bhi(lu.w) + bhi(ru.w) + a * w1.w) * t1.w;
  p += __shfl_xor(p, 8); p += __shfl_xor(p, 4);
  p += __shfl_xor(p, 2); p += __shfl_xor(p, 1);
  if ((lane & 15) == 0) esc[eid * 4 + (lane >> 4)] = p;
}

// ---------------- layer-1 edge scores (bf16, 256 ch)
__global__ __launch_bounds__(256) void score_l1(const u16* __restrict__ xl,
    const u16* __restrict__ xr, const float* __restrict__ ea,
    const float* __restrict__ we, const float* __restrict__ att,
    const int* __restrict__ ei, float* __restrict__ esc){
  int eid = blockIdx.x * 4 + (threadIdx.x >> 6);
  int lane = threadIdx.x & 63;
  int src = ei[eid], dst = ei[Ee + eid];
  float a = ea[eid];
  int c = lane << 2;
  uint2 lu = *(const uint2*)&xl[(size_t)src * 256 + c];
  uint2 ru = *(const uint2*)&xr[(size_t)dst * 256 + c];
  float4 w = *(const float4*)&we[c];
  float4 t = *(const float4*)&att[c];
  float p = 0.f;
  p += lrelu(blo(lu.x) + blo(ru.x) + a * w.x) * t.x;
  p += lrelu(bhi(lu.x) + bhi(ru.x) + a * w.y) * t.y;
  p += lrelu(blo(lu.y) + blo(ru.y) + a * w.z) * t.z;
  p += lrelu(bhi(lu.y) + bhi(ru.y) + a * w.w) * t.w;
  p += __shfl_xor(p, 8); p += __shfl_xor(p, 4);
  p += __shfl_xor(p, 2); p += __shfl_xor(p, 1);
  if ((lane & 15) == 0) esc[eid * 4 + (lane >> 4)] = p;
}

// ---------------- per-dst softmax over incoming edges
__global__ __launch_bounds__(256) void softmax_dst(float* __restrict__ esc,
    const int* __restrict__ offs, const int* __restrict__ eidx){
  int idx = blockIdx.x * 256 + threadIdx.x;
  if (idx >= Nn * 4) return;
  int n = idx >> 2, h = idx & 3;
  int s = offs[n], e = offs[n + 1];
  if (s == e) return;
  float m = -INFINITY;
  for (int i = s; i < e; i++) m = fmaxf(m, esc[eidx[i] * 4 + h]);
  float den = 0.f;
  for (int i = s; i < e; i++){
    int id = eidx[i] * 4 + h;
    float v = expf(esc[id] - m);
    esc[id] = v; den += v;
  }
  float inv = 1.f / (den + 1e-16f);
  for (int i = s; i < e; i++) esc[eidx[i] * 4 + h] *= inv;
}

// ---------------- layer-0 aggregation (bf16 gather, fp32 out), wave/dst
__global__ __launch_bounds__(256) void aggregate_l0(const u16* __restrict__ xl,
    const float* __restrict__ esc, const int* __restrict__ ei,
    const int* __restrict__ offs, const int* __restrict__ eidx,
    float* __restrict__ out){
  int n = blockIdx.x * 4 + (threadIdx.x >> 6);
  int lane = threadIdx.x & 63;
  int s = offs[n], e = offs[n + 1];
  int c = lane << 3, h = lane >> 4;
  float a0=0.f,a1=0.f,a2=0.f,a3=0.f,a4=0.f,a5=0.f,a6=0.f,a7=0.f;
  for (int i = s; i < e; i++){
    int eid = eidx[i];
    float alpha = esc[eid * 4 + h];
    int src = ei[eid];
    uint4 v = *(const uint4*)&xl[(size_t)src * 512 + c];
    a0 += alpha * blo(v.x); a1 += alpha * bhi(v.x);
    a2 += alpha * blo(v.y); a3 += alpha * bhi(v.y);
    a4 += alpha * blo(v.z); a5 += alpha * bhi(v.z);
    a6 += alpha * blo(v.w); a7 += alpha * bhi(v.w);
  }
  float4* op = (float4*)&out[(size_t)n * 512 + c];
  op[0] = make_float4(a0, a1, a2, a3);
  op[1] = make_float4(a4, a5, a6, a7);
}

// ---------------- layer-1 aggregation, head-mean folded, wave/dst
__global__ __launch_bounds__(256) void aggregate_l1(const u16* __restrict__ xl,
    const float* __restrict__ esc, const int* __restrict__ ei,
    const int* __restrict__ offs, const int* __restrict__ eidx,
    float* __restrict__ out){
  int n = blockIdx.x * 4 + (threadIdx.x >> 6);
  int lane = threadIdx.x & 63;   // output channel
  int s = offs[n], e = offs[n + 1];
  float acc = 0.f;
  for (int i = s; i < e; i++){
    int eid = eidx[i];
    int src = ei[eid];
    float4 al = *(const float4*)&esc[eid * 4];
    const u16* xp = &xl[(size_t)src * 256 + lane];
    acc += al.x * 0.25f * b2f(xp[0]);
    acc += al.y * 0.25f * b2f(xp[64]);
    acc += al.z * 0.25f * b2f(xp[128]);
    acc += al.w * 0.25f * b2f(xp[192]);
  }
  out[(size_t)n * 64 + lane] = acc;
}

// ---------------- batchnorm reduce
__global__ void bn_reduce(const float* __restrict__ X, float* __restrict__ stats,
                          int Nr, int C, int rpb){
  int tid = threadIdx.x;
  int c = tid % C, sub = tid / C, step = blockDim.x / C;
  float s = 0.f, s2 = 0.f;
  int rend = min((int)((blockIdx.x + 1) * rpb), Nr);
  for (int r = blockIdx.x * rpb + sub; r < rend; r += step){
    float v = X[(size_t)r * C + c];
    s += v; s2 += v * v;
  }
  atomicAdd(&stats[c], s);
  atomicAdd(&stats[C + c], s2);
}

// ---------------- BN+ELU -> bf16 out (layer 0 path feeds MFMA GEMM)
__global__ __launch_bounds__(256) void bn_apply_bf(const float* __restrict__ X,
    const float* __restrict__ stats, const float* __restrict__ g,
    const float* __restrict__ b, u16* __restrict__ Xb, int total, int C, float invN){
  int idx = blockIdx.x * 256 + threadIdx.x;
  if (idx >= total) return;
  int c = idx % C;
  float mean = stats[c] * invN;
  float var = stats[C + c] * invN - mean * mean;
  float inv = rsqrtf(var + 1e-5f);
  float v = (X[idx] - mean) * inv * g[c] + b[c];
  Xb[idx] = fbf(elu(v));
}

// ---------------- BN+ELU fp32 in place (layer 1 path)
__global__ __launch_bounds__(256) void bn_apply(float* __restrict__ X,
    const float* __restrict__ stats, const float* __restrict__ g,
    const float* __restrict__ b, int total, int C, float invN){
  int idx = blockIdx.x * 256 + threadIdx.x;
  if (idx >= total) return;
  int c = idx % C;
  float mean = stats[c] * invN;
  float var = stats[C + c] * invN - mean * mean;
  float inv = rsqrtf(var + 1e-5f);
  float v = (X[idx] - mean) * inv * g[c] + b[c];
  X[idx] = elu(v);
}

// ---------------- per-graph mean pool (block per graph, no atomics)
__global__ __launch_bounds__(256) void pool_graph(const float* __restrict__ h1,
    const int* __restrict__ goffs, float* __restrict__ emb, float* __restrict__ out_emb){
  int b = blockIdx.x;
  int s = goffs[b], e = goffs[b + 1];
  int c = threadIdx.x & 63, sub = threadIdx.x >> 6;
  float acc = 0.f;
  for (int n = s + sub; n < e; n += 4) acc += h1[(size_t)n * 64 + c];
  __shared__ float red[4][64];
  red[sub][c] = acc;
  __syncthreads();
  if (sub == 0){
    float v = red[0][c] + red[1][c] + red[2][c] + red[3][c];
    v /= fmaxf((float)(e - s), 1.0f);
    emb[b * 64 + c] = v;
    out_emb[b * 64 + c] = v;
  }
}

// ---------------- fused classifier with transposed weights (register-resident columns)
// One block, 256 threads. LDS: [0..4096) emb | [4096..12288) z1 chunk (64x128)
// phase3 overlay: [0..8448) z2 (64x132 padded). Partials at [12288..12800).
// W1T[256][64], W2T[128][256]: each thread bulk-loads its weight column as
// 16 independent float4 loads -> one memory latency per 64 weights instead of 64.
__global__ __launch_bounds__(256, 1) void classifier(
    const float* __restrict__ embg,
    const float* __restrict__ W1T, const float* __restrict__ b1,
    const float* __restrict__ g1, const float* __restrict__ bb1,
    const float* __restrict__ W2T, const float* __restrict__ b2,
    const float* __restrict__ g2, const float* __restrict__ bb2,
    const float* __restrict__ W3, const float* __restrict__ b3,
    float* __restrict__ out){
  __shared__ float smem[12800];
  float* emb = smem;              // 64*64
  float* z1  = smem + 4096;       // 64*128 (current chunk)
  float* z2  = smem;              // 64*132 (phase 3 overlay)
  float* ps  = smem + 12288;      // 256 partial sums
  float* ps2 = smem + 12544;      // 256 partial sumsq
  int t = threadIdx.x;
  int jj = t & 127;               // local channel
  int h  = t >> 7;                // batch half: rows [32h, 32h+32)
  for (int i = t; i < 1024; i += 256)
    ((float4*)emb)[i] = ((const float4*)embg)[i];
  __syncthreads();

  float acc2[32];
  #pragma unroll
  for (int i = 0; i < 32; i++) acc2[i] = 0.f;

  for (int c = 0; c < 2; c++){
    int j = c * 128 + jj;         // global z1 channel
    // ---- bulk-load W1 column j into registers (16 loads in flight) ----
    float w1r[64];
    {
      const float4* wp = (const float4*)&W1T[j * 64];
      #pragma unroll
      for (int q = 0; q < 16; q++){
        float4 v = wp[q];
        w1r[4*q] = v.x; w1r[4*q+1] = v.y; w1r[4*q+2] = v.z; w1r[4*q+3] = v.w;
      }
    }
    // ---- phase 1: z1[:, j] for this thread's 32 rows ----
    float acc[32];
    float bias = b1[j];
    #pragma unroll
    for (int i = 0; i < 32; i++) acc[i] = bias;
    #pragma unroll
    for (int i = 0; i < 32; i++){
      const float4* ep = (const float4*)&emb[(32 * h + i) * 64];
      #pragma unroll
      for (int q = 0; q < 16; q++){
        float4 e = ep[q];
        acc[i] += e.x * w1r[4*q] + e.y * w1r[4*q+1]
                + e.z * w1r[4*q+2] + e.w * w1r[4*q+3];
      }
    }
    float s = 0.f, s2 = 0.f;
    #pragma unroll
    for (int i = 0; i < 32; i++){ s += acc[i]; s2 += acc[i] * acc[i]; }
    ps[t] = s; ps2[t] = s2;
    __syncthreads();
    float S = s + ps[t ^ 128], S2 = s2 + ps2[t ^ 128];
    float mean = S * (1.f / 64.f);
    float var = S2 * (1.f / 64.f) - mean * mean;
    float inv = rsqrtf(var + 1e-5f);
    float sc = g1[j] * inv, sh = bb1[j] - mean * sc;
    #pragma unroll
    for (int i = 0; i < 32; i++)
      z1[(32 * h + i) * 128 + jj] = elu(acc[i] * sc + sh);
    __syncthreads();
    // ---- phase 2 partial: z2 contributions from this chunk's 128 k values ----
    #pragma unroll
    for (int cc = 0; cc < 2; cc++){
      float w2r[64];
      const float4* w2p = (const float4*)&W2T[jj * 256 + c * 128 + cc * 64];
      #pragma unroll
      for (int q = 0; q < 16; q++){
        float4 v = w2p[q];
        w2r[4*q] = v.x; w2r[4*q+1] = v.y; w2r[4*q+2] = v.z; w2r[4*q+3] = v.w;
      }
      #pragma unroll
      for (int i = 0; i < 32; i++){
        const float4* zp = (const float4*)&z1[(32 * h + i) * 128 + cc * 64];
        #pragma unroll
        for (int q = 0; q < 16; q++){
          float4 zv = zp[q];
          acc2[i] += zv.x * w2r[4*q] + zv.y * w2r[4*q+1]
                   + zv.z * w2r[4*q+2] + zv.w * w2r[4*q+3];
        }
      }
    }
    __syncthreads();   // chunk done before z1 overwritten next iter
  }

  // ---- BN2 + ELU -> z2 (overlay; all z1/emb reads complete) ----
  float bias2 = b2[jj];
  #pragma unroll
  for (int i = 0; i < 32; i++) acc2[i] += bias2;
  float s = 0.f, s2 = 0.f;
  #pragma unroll
  for (int i = 0; i < 32; i++){ s += acc2[i]; s2 += acc2[i] * acc2[i]; }
  ps[t] = s; ps2[t] = s2;
  __syncthreads();
  float S = s + ps[t ^ 128], S2 = s2 + ps2[t ^ 128];
  float mean = S * (1.f / 64.f);
  float var = S2 * (1.f / 64.f) - mean * mean;
  float inv = rsqrtf(var + 1e-5f);
  float sc = g2[jj] * inv, sh = bb2[jj] - mean * sc;
  __syncthreads();               // everyone past ps reads before z2 overlay write
  #pragma unroll
  for (int i = 0; i < 32; i++)
    z2[(32 * h + i) * 132 + jj] = elu(acc2[i] * sc + sh);
  __syncthreads();

  // ---- phase 3: logits ----
  if (t < 128){
    int o = t >> 6, b = t & 63;
    float a = b3[o];
    for (int j2 = 0; j2 < 128; j2++) a += z2[b * 132 + j2] * W3[j2 * 2 + o];
    out[b * 2 + o] = a;
  }
}

extern "C" void kernel_launch(void* const* d_in, const int* in_sizes, int n_in,
                              void* d_out, int out_size, void* d_ws, size_t ws_size,
                              hipStream_t stream){
  const float* x      = (const float*)d_in[0];
  const int*   ei     = (const int*)d_in[1];
  const float* ea     = (const float*)d_in[2];
  const int*   batch  = (const int*)d_in[3];
  const float* g0_wl  = (const float*)d_in[4];
  const float* g0_wr  = (const float*)d_in[5];
  const float* g0_we  = (const float*)d_in[6];
  const float* g0_att = (const float*)d_in[7];
  const float* bn0_g  = (const float*)d_in[9];
  const float* bn0_b  = (const float*)d_in[10];
  const float* g1_wl  = (const float*)d_in[11];
  const float* g1_wr  = (const float*)d_in[12];
  const float* g1_we  = (const float*)d_in[13];
  const float* g1_att = (const float*)d_in[14];
  const float* bn1_g  = (const float*)d_in[16];
  const float* bn1_b  = (const float*)d_in[17];
  const float* c_w1   = (const float*)d_in[18];
  const float* c_b1   = (const float*)d_in[19];
  const float* cbn1_g = (const float*)d_in[20];
  const float* cbn1_b = (const float*)d_in[21];
  const float* c_w2   = (const float*)d_in[22];
  const float* c_b2   = (const float*)d_in[23];
  const float* cbn2_g = (const float*)d_in[24];
  const float* cbn2_b = (const float*)d_in[25];
  const float* c_w3   = (const float*)d_in[26];
  const float* c_b3   = (const float*)d_in[27];
  float* out = (float*)d_out;
  float* ws = (float*)d_ws;

  u16* xb   = (u16*)(ws + XB);
  u16* xl0b = (u16*)(ws + XL0B);
  u16* xr0b = (u16*)(ws + XR0B);
  u16* h0b  = (u16*)(ws + H0B);
  u16* wt0a = (u16*)(ws + WTS);
  u16* wt0b = wt0a + 131072;
  u16* wt1a = wt0a + 262144;
  u16* wt1b = wt0a + 393216;
  float* w1t = ws + W1TF;
  float* w2t = ws + W2TF;
  int* offs   = (int*)(ws + CSRI);
  int* cursor = offs + (Nn + 1);
  int* eidx   = cursor + Nn;
  int* goffs  = eidx + Ee;          // B+1

  hipMemsetAsync(cursor, 0, Nn * sizeof(int), stream);
  hipMemsetAsync(ws + SMALL, 0, ZCNT * sizeof(float), stream);

  // ---- conversions ----
  conv_bf<<<(Nn * 256 / 4 + 255) / 256, 256, 0, stream>>>(x, xb, Nn * 256 / 4);
  conv_wt<<<512, 256, 0, stream>>>(g0_wl, wt0a, 256, 512);
  conv_wt<<<512, 256, 0, stream>>>(g0_wr, wt0b, 256, 512);
  conv_wt<<<512, 256, 0, stream>>>(g1_wl, wt1a, 512, 256);
  conv_wt<<<512, 256, 0, stream>>>(g1_wr, wt1b, 512, 256);
  conv_wtf<<<64, 256, 0, stream>>>(c_w1, w1t, 64, 256);
  conv_wtf<<<128, 256, 0, stream>>>(c_w2, w2t, 256, 128);

  // ---- CSR by destination + graph bounds ----
  csr_hist<<<(Ee + 255) / 256, 256, 0, stream>>>(ei, cursor);
  csr_scan<<<1, 1024, 0, stream>>>(offs, cursor);
  csr_fill<<<(Ee + 255) / 256, 256, 0, stream>>>(ei, cursor, eidx);
  graph_bounds<<<(Nn + 255) / 256, 256, 0, stream>>>(batch, goffs);

  // ---- layer 0 ----
  gemm_mfma<<<dim3(4, 157, 2), 256, 0, stream>>>(xb, wt0a, wt0b, xl0b, xr0b,
                                                 Nn, 256, 512);
  score_l0<<<Ee / 4, 256, 0, stream>>>(xl0b, xr0b, ea, g0_we, g0_att, ei, ws + ESC);
  softmax_dst<<<(Nn * 4 + 255) / 256, 256, 0, stream>>>(ws + ESC, offs, eidx);
  aggregate_l0<<<Nn / 4, 256, 0, stream>>>(xl0b, ws + ESC, ei, offs, eidx, ws + OUT0);
  bn_reduce<<<200, 512, 0, stream>>>(ws + OUT0, ws + BN0S, Nn, 512, 100);
  bn_apply_bf<<<40000, 256, 0, stream>>>(ws + OUT0, ws + BN0S, bn0_g, bn0_b, h0b,
                                         Nn * 512, 512, 1.f / Nn);
  // ---- layer 1 ----
  gemm_mfma<<<dim3(2, 157, 2), 256, 0, stream>>>(h0b, wt1a, wt1b, xl0b, xr0b,
                                                 Nn, 512, 256);
  score_l1<<<Ee / 4, 256, 0, stream>>>(xl0b, xr0b, ea, g1_we, g1_att, ei, ws + ESC);
  softmax_dst<<<(Nn * 4 + 255) / 256, 256, 0, stream>>>(ws + ESC, offs, eidx);
  aggregate_l1<<<Nn / 4, 256, 0, stream>>>(xl0b, ws + ESC, ei, offs, eidx, ws + OUT1);
  bn_reduce<<<50, 256, 0, stream>>>(ws + OUT1, ws + BN1S, Nn, 64, 400);
  bn_apply<<<5000, 256, 0, stream>>>(ws + OUT1, ws + BN1S, bn1_g, bn1_b,
                                     Nn * 64, 64, 1.f / Nn);
  // ---- pool + fused classifier ----
  pool_graph<<<Bb, 256, 0, stream>>>(ws + OUT1, goffs, ws + EMB, out + 128);
  classifier<<<1, 256, 0, stream>>>(ws + EMB, w1t, c_b1, cbn1_g, cbn1_b,
                                    w2t, c_b2, cbn2_g, cbn2_b, c_w3, c_b3, out);
}

// Round 7
// 546.036 us; speedup vs baseline: 1.5284x; 1.5284x over previous
//
#include <hip/hip_runtime.h>
#include <cmath>

#define Nn 20000
#define Ee 320000
#define Bb 64

typedef unsigned short u16;
typedef __bf16 bf16x8 __attribute__((ext_vector_type(8)));
typedef float f32x4 __attribute__((ext_vector_type(4)));

// ---------------- workspace layout (float units) ----------------
static const size_t OUT0 = 0;                    // N*512 fp32
static const size_t XL0B = 10240000;             // N*512 bf16 (layer1 reuses as N*256)
static const size_t XR0B = 15360000;             // N*512 bf16
static const size_t H0B  = 20480000;             // N*512 bf16 (post-BN h0)
static const size_t XB   = 25600000;             // N*256 bf16
static const size_t WTS  = 28160000;             // 4 x 131072 u16 (transposed bf16 weights)
static const size_t OUT1 = 28422144;             // N*64 fp32
static const size_t CSRI = 30982144;             // ints: offs[N+1], cursor[N], eidx[E], goffs[B+1]
static const size_t SMALL= 31342272;
static const size_t BN0S = SMALL;                // 1024
static const size_t BN1S = BN0S + 1024;          // 128
static const size_t ZCNT = 1152;                 // floats to zero (BN stats only)
static const size_t EMB  = BN1S + 128;           // 64*64 emb
static const size_t Z1C  = EMB + 4096;           // 64*256 classifier z1
static const size_t Z2C  = Z1C + 16384;          // 64*128 classifier z2

__device__ __forceinline__ float lrelu(float x){ return x > 0.f ? x : 0.2f * x; }
__device__ __forceinline__ float elu(float x){ return x > 0.f ? x : expm1f(x); }
__device__ __forceinline__ u16 fbf(float f){           // fp32 -> bf16 RNE
  unsigned u = __float_as_uint(f);
  return (u16)((u + 0x7fffu + ((u >> 16) & 1u)) >> 16);
}
__device__ __forceinline__ float blo(unsigned u){ return __uint_as_float(u << 16); }
__device__ __forceinline__ float bhi(unsigned u){ return __uint_as_float(u & 0xffff0000u); }

// ---------------- fp32 -> bf16 (n multiple of 4) ----------------
__global__ __launch_bounds__(256) void conv_bf(const float* __restrict__ src,
                                               u16* __restrict__ dst, int n4){
  int i = blockIdx.x * 256 + threadIdx.x;
  if (i < n4){
    float4 v = ((const float4*)src)[i];
    ushort4 o; o.x = fbf(v.x); o.y = fbf(v.y); o.z = fbf(v.z); o.w = fbf(v.w);
    ((ushort4*)dst)[i] = o;
  }
}

// ---------------- W[K][N] fp32 -> WT[N][K] bf16 ----------------
__global__ __launch_bounds__(256) void conv_wt(const float* __restrict__ W,
                                               u16* __restrict__ WT, int K, int N){
  int i = blockIdx.x * 256 + threadIdx.x;
  if (i < K * N){
    int n = i / K, k = i - n * K;
    WT[i] = fbf(W[k * N + n]);
  }
}

// ---------------- MFMA GEMM: O[M][Nc] = A[M][K] @ WT[Nc][K]^T, all bf16, fp32 acc
__global__ __launch_bounds__(256) void gemm_mfma(const u16* __restrict__ A,
    const u16* __restrict__ WTa, const u16* __restrict__ WTb,
    u16* __restrict__ Oa, u16* __restrict__ Ob, int M, int K, int Nc){
  const u16* WT = blockIdx.z ? WTb : WTa;
  u16* O = blockIdx.z ? Ob : Oa;
  __shared__ u16 As[128 * 40];   // row stride 40 u16 = 80B -> 2-way bank alias (free)
  __shared__ u16 Bs[128 * 40];
  int tid = threadIdx.x;
  int m0 = blockIdx.y * 128, n0 = blockIdx.x * 128;
  int lane = tid & 63, w = tid >> 6;
  int wr = (w >> 1) * 64, wc = (w & 1) * 64;
  int l16 = lane & 15, kq = lane >> 4;
  f32x4 acc[4][4] = {};
  int srow = tid >> 2, scol = (tid & 3) * 8;
  for (int kt = 0; kt < K; kt += 32){
    #pragma unroll
    for (int r = 0; r < 2; r++){
      int row = r * 64 + srow;
      uint4 av = make_uint4(0u, 0u, 0u, 0u);
      int gr = m0 + row;
      if (gr < M) av = *(const uint4*)&A[(size_t)gr * K + kt + scol];
      *(uint4*)&As[row * 40 + scol] = av;
      uint4 bv = *(const uint4*)&WT[(size_t)(n0 + row) * K + kt + scol];
      *(uint4*)&Bs[row * 40 + scol] = bv;
    }
    __syncthreads();
    bf16x8 af[4], bfr[4];
    #pragma unroll
    for (int i = 0; i < 4; i++){
      af[i]  = *(bf16x8*)&As[(wr + i * 16 + l16) * 40 + kq * 8];
      bfr[i] = *(bf16x8*)&Bs[(wc + i * 16 + l16) * 40 + kq * 8];
    }
    #pragma unroll
    for (int i = 0; i < 4; i++)
      #pragma unroll
      for (int j = 0; j < 4; j++)
        acc[i][j] = __builtin_amdgcn_mfma_f32_16x16x32_bf16(af[i], bfr[j], acc[i][j], 0, 0, 0);
    __syncthreads();
  }
  #pragma unroll
  for (int i = 0; i < 4; i++){
    #pragma unroll
    for (int rg = 0; rg < 4; rg++){
      int row = m0 + wr + i * 16 + kq * 4 + rg;
      if (row < M){
        #pragma unroll
        for (int j = 0; j < 4; j++){
          int col = n0 + wc + j * 16 + l16;
          O[(size_t)row * Nc + col] = fbf(acc[i][j][rg]);
        }
      }
    }
  }
}

// ---------------- CSR build ----------------
__global__ __launch_bounds__(256) void csr_hist(const int* __restrict__ ei,
                                                int* __restrict__ cursor){
  int e = blockIdx.x * 256 + threadIdx.x;
  if (e < Ee) atomicAdd(&cursor[ei[Ee + e]], 1);
}

__global__ __launch_bounds__(1024) void csr_scan(int* __restrict__ offs,
                                                 int* __restrict__ cursor){
  __shared__ int part[1024];
  int t = threadIdx.x;
  int base = t * 20;
  int loc[20];
  int s = 0;
  #pragma unroll
  for (int i = 0; i < 20; i++){
    int idx = base + i;
    int v = (idx < Nn) ? cursor[idx] : 0;
    loc[i] = s; s += v;
  }
  part[t] = s;
  __syncthreads();
  for (int off = 1; off < 1024; off <<= 1){
    int v = 0;
    if (t >= off) v = part[t - off];
    __syncthreads();
    if (t >= off) part[t] += v;
    __syncthreads();
  }
  int pre = (t == 0) ? 0 : part[t - 1];
  #pragma unroll
  for (int i = 0; i < 20; i++){
    int idx = base + i;
    if (idx < Nn){ offs[idx] = pre + loc[i]; cursor[idx] = pre + loc[i]; }
  }
  if (t == 1023) offs[Nn] = part[1023];
}

__global__ __launch_bounds__(256) void csr_fill(const int* __restrict__ ei,
    int* __restrict__ cursor, int* __restrict__ eidx){
  int e = blockIdx.x * 256 + threadIdx.x;
  if (e < Ee){
    int d = ei[Ee + e];
    int p = atomicAdd(&cursor[d], 1);
    eidx[p] = e;
  }
}

// ---------------- graph boundaries from sorted batch
__global__ __launch_bounds__(256) void graph_bounds(const int* __restrict__ batch,
                                                    int* __restrict__ goffs){
  int i = blockIdx.x * 256 + threadIdx.x;
  if (i >= Nn) return;
  int b1 = batch[i];
  int b0 = (i == 0) ? -1 : batch[i - 1];
  for (int b = b0 + 1; b <= b1; b++) goffs[b] = i;
  if (i == Nn - 1)
    for (int b = b1 + 1; b <= Bb; b++) goffs[b] = Nn;
}

// ---------------- fused layer-0: score + online-softmax + aggregate, wave/dst
// xr[dst] cached in registers; xl[src] loaded once per edge for both score & agg.
__global__ __launch_bounds__(256) void fused_l0(const u16* __restrict__ xl,
    const u16* __restrict__ xr, const float* __restrict__ ea,
    const float* __restrict__ we, const float* __restrict__ att,
    const int* __restrict__ ei, const int* __restrict__ offs,
    const int* __restrict__ eidx, float* __restrict__ out){
  int n = blockIdx.x * 4 + (threadIdx.x >> 6);
  int lane = threadIdx.x & 63;
  int s = offs[n], e = offs[n + 1];
  int c = lane << 3;            // 8 channels/lane, head = lane>>4
  uint4 ru = *(const uint4*)&xr[(size_t)n * 512 + c];
  float r0=blo(ru.x), r1=bhi(ru.x), r2=blo(ru.y), r3=bhi(ru.y),
        r4=blo(ru.z), r5=bhi(ru.z), r6=blo(ru.w), r7=bhi(ru.w);
  float4 w0 = *(const float4*)&we[c],  w1 = *(const float4*)&we[c + 4];
  float4 t0 = *(const float4*)&att[c], t1 = *(const float4*)&att[c + 4];
  float m = -INFINITY, d = 0.f;
  float a0=0.f,a1=0.f,a2=0.f,a3=0.f,a4=0.f,a5=0.f,a6=0.f,a7=0.f;
  for (int i = s; i < e; i++){
    int eid = eidx[i];
    int src = ei[eid];
    float av = ea[eid];
    uint4 lu = *(const uint4*)&xl[(size_t)src * 512 + c];
    float x0=blo(lu.x), x1=bhi(lu.x), x2=blo(lu.y), x3=bhi(lu.y),
          x4=blo(lu.z), x5=bhi(lu.z), x6=blo(lu.w), x7=bhi(lu.w);
    float p = lrelu(x0+r0+av*w0.x)*t0.x + lrelu(x1+r1+av*w0.y)*t0.y
            + lrelu(x2+r2+av*w0.z)*t0.z + lrelu(x3+r3+av*w0.w)*t0.w
            + lrelu(x4+r4+av*w1.x)*t1.x + lrelu(x5+r5+av*w1.y)*t1.y
            + lrelu(x6+r6+av*w1.z)*t1.z + lrelu(x7+r7+av*w1.w)*t1.w;
    p += __shfl_xor(p, 8); p += __shfl_xor(p, 4);
    p += __shfl_xor(p, 2); p += __shfl_xor(p, 1);   // per-head score, all 16 lanes
    float mn = fmaxf(m, p);
    float scale = expf(m - mn);    // first iter: exp(-inf)=0
    float ee = expf(p - mn);
    d = d * scale + ee;
    a0 = a0*scale + ee*x0; a1 = a1*scale + ee*x1;
    a2 = a2*scale + ee*x2; a3 = a3*scale + ee*x3;
    a4 = a4*scale + ee*x4; a5 = a5*scale + ee*x5;
    a6 = a6*scale + ee*x6; a7 = a7*scale + ee*x7;
    m = mn;
  }
  float inv = 1.f / (d + 1e-16f);   // empty segment: acc=0 -> writes 0
  float4* op = (float4*)&out[(size_t)n * 512 + c];
  op[0] = make_float4(a0*inv, a1*inv, a2*inv, a3*inv);
  op[1] = make_float4(a4*inv, a5*inv, a6*inv, a7*inv);
}

// ---------------- fused layer-1: score + online-softmax + aggregate + head-mean
__global__ __launch_bounds__(256) void fused_l1(const u16* __restrict__ xl,
    const u16* __restrict__ xr, const float* __restrict__ ea,
    const float* __restrict__ we, const float* __restrict__ att,
    const int* __restrict__ ei, const int* __restrict__ offs,
    const int* __restrict__ eidx, float* __restrict__ out){
  int n = blockIdx.x * 4 + (threadIdx.x >> 6);
  int lane = threadIdx.x & 63;
  int s = offs[n], e = offs[n + 1];
  int c = lane << 2;            // 4 channels/lane = head (lane>>4), in-head (lane&15)*4
  uint2 ru = *(const uint2*)&xr[(size_t)n * 256 + c];
  float r0=blo(ru.x), r1=bhi(ru.x), r2=blo(ru.y), r3=bhi(ru.y);
  float4 w  = *(const float4*)&we[c];
  float4 tt = *(const float4*)&att[c];
  float m = -INFINITY, d = 0.f;
  float a0=0.f,a1=0.f,a2=0.f,a3=0.f;
  for (int i = s; i < e; i++){
    int eid = eidx[i];
    int src = ei[eid];
    float av = ea[eid];
    uint2 lu = *(const uint2*)&xl[(size_t)src * 256 + c];
    float x0=blo(lu.x), x1=bhi(lu.x), x2=blo(lu.y), x3=bhi(lu.y);
    float p = lrelu(x0+r0+av*w.x)*tt.x + lrelu(x1+r1+av*w.y)*tt.y
            + lrelu(x2+r2+av*w.z)*tt.z + lrelu(x3+r3+av*w.w)*tt.w;
    p += __shfl_xor(p, 8); p += __shfl_xor(p, 4);
    p += __shfl_xor(p, 2); p += __shfl_xor(p, 1);
    float mn = fmaxf(m, p);
    float scale = expf(m - mn);
    float ee = expf(p - mn);
    d = d * scale + ee;
    a0 = a0*scale + ee*x0; a1 = a1*scale + ee*x1;
    a2 = a2*scale + ee*x2; a3 = a3*scale + ee*x3;
    m = mn;
  }
  float inv = 0.25f / (d + 1e-16f);  // fold head-mean
  float v0 = a0*inv, v1 = a1*inv, v2 = a2*inv, v3 = a3*inv;
  v0 += __shfl_xor(v0, 16); v0 += __shfl_xor(v0, 32);   // sum over 4 heads
  v1 += __shfl_xor(v1, 16); v1 += __shfl_xor(v1, 32);
  v2 += __shfl_xor(v2, 16); v2 += __shfl_xor(v2, 32);
  v3 += __shfl_xor(v3, 16); v3 += __shfl_xor(v3, 32);
  if (lane < 16)
    *(float4*)&out[(size_t)n * 64 + lane * 4] = make_float4(v0, v1, v2, v3);
}

// ---------------- batchnorm reduce
__global__ void bn_reduce(const float* __restrict__ X, float* __restrict__ stats,
                          int Nr, int C, int rpb){
  int tid = threadIdx.x;
  int c = tid % C, sub = tid / C, step = blockDim.x / C;
  float s = 0.f, s2 = 0.f;
  int rend = min((int)((blockIdx.x + 1) * rpb), Nr);
  for (int r = blockIdx.x * rpb + sub; r < rend; r += step){
    float v = X[(size_t)r * C + c];
    s += v; s2 += v * v;
  }
  atomicAdd(&stats[c], s);
  atomicAdd(&stats[C + c], s2);
}

// ---------------- BN+ELU -> bf16 out (layer 0 path feeds MFMA GEMM)
__global__ __launch_bounds__(256) void bn_apply_bf(const float* __restrict__ X,
    const float* __restrict__ stats, const float* __restrict__ g,
    const float* __restrict__ b, u16* __restrict__ Xb, int total, int C, float invN){
  int idx = blockIdx.x * 256 + threadIdx.x;
  if (idx >= total) return;
  int c = idx % C;
  float mean = stats[c] * invN;
  float var = stats[C + c] * invN - mean * mean;
  float inv = rsqrtf(var + 1e-5f);
  float v = (X[idx] - mean) * inv * g[c] + b[c];
  Xb[idx] = fbf(elu(v));
}

// ---------------- BN+ELU fp32 in place (layer 1 path)
__global__ __launch_bounds__(256) void bn_apply(float* __restrict__ X,
    const float* __restrict__ stats, const float* __restrict__ g,
    const float* __restrict__ b, int total, int C, float invN){
  int idx = blockIdx.x * 256 + threadIdx.x;
  if (idx >= total) return;
  int c = idx % C;
  float mean = stats[c] * invN;
  float var = stats[C + c] * invN - mean * mean;
  float inv = rsqrtf(var + 1e-5f);
  float v = (X[idx] - mean) * inv * g[c] + b[c];
  X[idx] = elu(v);
}

// ---------------- per-graph mean pool (block per graph, no atomics)
__global__ __launch_bounds__(256) void pool_graph(const float* __restrict__ h1,
    const int* __restrict__ goffs, float* __restrict__ emb, float* __restrict__ out_emb){
  int b = blockIdx.x;
  int s = goffs[b], e = goffs[b + 1];
  int c = threadIdx.x & 63, sub = threadIdx.x >> 6;
  float acc = 0.f;
  for (int n = s + sub; n < e; n += 4) acc += h1[(size_t)n * 64 + c];
  __shared__ float red[4][64];
  red[sub][c] = acc;
  __syncthreads();
  if (sub == 0){
    float v = red[0][c] + red[1][c] + red[2][c] + red[3][c];
    v /= fmaxf((float)(e - s), 1.0f);
    emb[b * 64 + c] = v;
    out_emb[b * 64 + c] = v;
  }
}

// ---------------- classifier stage 1, parallel: 16 blocks x 16 channels.
// Block owns channels [bk*16, bk*16+16) for ALL 64 rows -> BN is block-local.
__global__ __launch_bounds__(256) void mlp1_par(const float* __restrict__ emb,
    const float* __restrict__ W1, const float* __restrict__ b1,
    const float* __restrict__ g, const float* __restrict__ bb,
    float* __restrict__ z1){
  int t = threadIdx.x;
  int jj = t & 15, rg = t >> 4;            // rg -> rows [rg*4, rg*4+4)
  int j = blockIdx.x * 16 + jj;
  float acc[4];
  float bias = b1[j];
  #pragma unroll
  for (int r = 0; r < 4; r++) acc[r] = bias;
  for (int k = 0; k < 64; k++){
    float w = W1[k * 256 + j];
    #pragma unroll
    for (int r = 0; r < 4; r++) acc[r] += emb[(rg * 4 + r) * 64 + k] * w;
  }
  __shared__ float ssum[16][16], ssq[16][16];
  float s = 0.f, s2 = 0.f;
  #pragma unroll
  for (int r = 0; r < 4; r++){ s += acc[r]; s2 += acc[r] * acc[r]; }
  ssum[rg][jj] = s; ssq[rg][jj] = s2;
  __syncthreads();
  float S = 0.f, S2 = 0.f;
  #pragma unroll
  for (int q = 0; q < 16; q++){ S += ssum[q][jj]; S2 += ssq[q][jj]; }
  float mean = S * (1.f / 64.f);
  float var = S2 * (1.f / 64.f) - mean * mean;
  float inv = rsqrtf(var + 1e-5f);
  float sc = g[j] * inv, sh = bb[j] - mean * sc;
  #pragma unroll
  for (int r = 0; r < 4; r++)
    z1[(rg * 4 + r) * 256 + j] = elu(acc[r] * sc + sh);
}

// ---------------- classifier stage 2, parallel: 8 blocks x 16 channels, K=256
__global__ __launch_bounds__(256) void mlp2_par(const float* __restrict__ z1,
    const float* __restrict__ W2, const float* __restrict__ b2,
    const float* __restrict__ g, const float* __restrict__ bb,
    float* __restrict__ z2){
  int t = threadIdx.x;
  int jj = t & 15, rg = t >> 4;
  int j = blockIdx.x * 16 + jj;
  float acc[4];
  float bias = b2[j];
  #pragma unroll
  for (int r = 0; r < 4; r++) acc[r] = bias;
  for (int k = 0; k < 256; k++){
    float w = W2[k * 128 + j];
    #pragma unroll
    for (int r = 0; r < 4; r++) acc[r] += z1[(rg * 4 + r) * 256 + k] * w;
  }
  __shared__ float ssum[16][16], ssq[16][16];
  float s = 0.f, s2 = 0.f;
  #pragma unroll
  for (int r = 0; r < 4; r++){ s += acc[r]; s2 += acc[r] * acc[r]; }
  ssum[rg][jj] = s; ssq[rg][jj] = s2;
  __syncthreads();
  float S = 0.f, S2 = 0.f;
  #pragma unroll
  for (int q = 0; q < 16; q++){ S += ssum[q][jj]; S2 += ssq[q][jj]; }
  float mean = S * (1.f / 64.f);
  float var = S2 * (1.f / 64.f) - mean * mean;
  float inv = rsqrtf(var + 1e-5f);
  float sc = g[j] * inv, sh = bb[j] - mean * sc;
  #pragma unroll
  for (int r = 0; r < 4; r++)
    z2[(rg * 4 + r) * 128 + j] = elu(acc[r] * sc + sh);
}

// ---------------- classifier stage 3: logits
__global__ __launch_bounds__(128) void mlp3(const float* __restrict__ z2,
    const float* __restrict__ W3, const float* __restrict__ b3, float* __restrict__ out){
  int tid = threadIdx.x;
  int b = tid >> 1, o = tid & 1;
  float acc = b3[o];
  for (int k = 0; k < 128; k++) acc += z2[b * 128 + k] * W3[k * 2 + o];
  out[b * 2 + o] = acc;
}

extern "C" void kernel_launch(void* const* d_in, const int* in_sizes, int n_in,
                              void* d_out, int out_size, void* d_ws, size_t ws_size,
                              hipStream_t stream){
  const float* x      = (const float*)d_in[0];
  const int*   ei     = (const int*)d_in[1];
  const float* ea     = (const float*)d_in[2];
  const int*   batch  = (const int*)d_in[3];
  const float* g0_wl  = (const float*)d_in[4];
  const float* g0_wr  = (const float*)d_in[5];
  const float* g0_we  = (const float*)d_in[6];
  const float* g0_att = (const float*)d_in[7];
  const float* bn0_g  = (const float*)d_in[9];
  const float* bn0_b  = (const float*)d_in[10];
  const float* g1_wl  = (const float*)d_in[11];
  const float* g1_wr  = (const float*)d_in[12];
  const float* g1_we  = (const float*)d_in[13];
  const float* g1_att = (const float*)d_in[14];
  const float* bn1_g  = (const float*)d_in[16];
  const float* bn1_b  = (const float*)d_in[17];
  const float* c_w1   = (const float*)d_in[18];
  const float* c_b1   = (const float*)d_in[19];
  const float* cbn1_g = (const float*)d_in[20];
  const float* cbn1_b = (const float*)d_in[21];
  const float* c_w2   = (const float*)d_in[22];
  const float* c_b2   = (const float*)d_in[23];
  const float* cbn2_g = (const float*)d_in[24];
  const float* cbn2_b = (const float*)d_in[25];
  const float* c_w3   = (const float*)d_in[26];
  const float* c_b3   = (const float*)d_in[27];
  float* out = (float*)d_out;
  float* ws = (float*)d_ws;

  u16* xb   = (u16*)(ws + XB);
  u16* xl0b = (u16*)(ws + XL0B);
  u16* xr0b = (u16*)(ws + XR0B);
  u16* h0b  = (u16*)(ws + H0B);
  u16* wt0a = (u16*)(ws + WTS);
  u16* wt0b = wt0a + 131072;
  u16* wt1a = wt0a + 262144;
  u16* wt1b = wt0a + 393216;
  int* offs   = (int*)(ws + CSRI);
  int* cursor = offs + (Nn + 1);
  int* eidx   = cursor + Nn;
  int* goffs  = eidx + Ee;          // B+1

  hipMemsetAsync(cursor, 0, Nn * sizeof(int), stream);
  hipMemsetAsync(ws + SMALL, 0, ZCNT * sizeof(float), stream);

  // ---- conversions ----
  conv_bf<<<(Nn * 256 / 4 + 255) / 256, 256, 0, stream>>>(x, xb, Nn * 256 / 4);
  conv_wt<<<512, 256, 0, stream>>>(g0_wl, wt0a, 256, 512);
  conv_wt<<<512, 256, 0, stream>>>(g0_wr, wt0b, 256, 512);
  conv_wt<<<512, 256, 0, stream>>>(g1_wl, wt1a, 512, 256);
  conv_wt<<<512, 256, 0, stream>>>(g1_wr, wt1b, 512, 256);

  // ---- CSR by destination + graph bounds ----
  csr_hist<<<(Ee + 255) / 256, 256, 0, stream>>>(ei, cursor);
  csr_scan<<<1, 1024, 0, stream>>>(offs, cursor);
  csr_fill<<<(Ee + 255) / 256, 256, 0, stream>>>(ei, cursor, eidx);
  graph_bounds<<<(Nn + 255) / 256, 256, 0, stream>>>(batch, goffs);

  // ---- layer 0 ----
  gemm_mfma<<<dim3(4, 157, 2), 256, 0, stream>>>(xb, wt0a, wt0b, xl0b, xr0b,
                                                 Nn, 256, 512);
  fused_l0<<<Nn / 4, 256, 0, stream>>>(xl0b, xr0b, ea, g0_we, g0_att, ei,
                                       offs, eidx, ws + OUT0);
  bn_reduce<<<200, 512, 0, stream>>>(ws + OUT0, ws + BN0S, Nn, 512, 100);
  bn_apply_bf<<<40000, 256, 0, stream>>>(ws + OUT0, ws + BN0S, bn0_g, bn0_b, h0b,
                                         Nn * 512, 512, 1.f / Nn);
  // ---- layer 1 ----
  gemm_mfma<<<dim3(2, 157, 2), 256, 0, stream>>>(h0b, wt1a, wt1b, xl0b, xr0b,
                                                 Nn, 512, 256);
  fused_l1<<<Nn / 4, 256, 0, stream>>>(xl0b, xr0b, ea, g1_we, g1_att, ei,
                                       offs, eidx, ws + OUT1);
  bn_reduce<<<50, 256, 0, stream>>>(ws + OUT1, ws + BN1S, Nn, 64, 400);
  bn_apply<<<5000, 256, 0, stream>>>(ws + OUT1, ws + BN1S, bn1_g, bn1_b,
                                     Nn * 64, 64, 1.f / Nn);
  // ---- pool + parallel classifier ----
  pool_graph<<<Bb, 256, 0, stream>>>(ws + OUT1, goffs, ws + EMB, out + 128);
  mlp1_par<<<16, 256, 0, stream>>>(ws + EMB, c_w1, c_b1, cbn1_g, cbn1_b, ws + Z1C);
  mlp2_par<<<8, 256, 0, stream>>>(ws + Z1C, c_w2, c_b2, cbn2_g, cbn2_b, ws + Z2C);
  mlp3<<<1, 128, 0, stream>>>(ws + Z2C, c_w3, c_b3, out);
}

// Round 8
// 503.544 us; speedup vs baseline: 1.6573x; 1.0844x over previous
//
#include <hip/hip_runtime.h>
#include <cmath>

#define Nn 20000
#define Ee 320000
#define Bb 64

typedef unsigned short u16;
typedef __bf16 bf16x8 __attribute__((ext_vector_type(8)));
typedef float f32x4 __attribute__((ext_vector_type(4)));

// ---------------- workspace layout (float units) ----------------
static const size_t OUT0 = 0;                    // N*512 fp32
static const size_t XL0B = 10240000;             // N*512 bf16 (layer1 reuses as N*256)
static const size_t XR0B = 15360000;             // N*512 bf16
static const size_t H0B  = 20480000;             // N*512 bf16 (post-BN h0)
static const size_t XB   = 25600000;             // N*256 bf16
static const size_t WTS  = 28160000;             // 4 x 131072 u16 (transposed bf16 weights)
static const size_t OUT1 = 28422144;             // N*64 fp32
static const size_t CSRI = 30982144;             // ints: offs[N+1], cursor[N], eidx[E], goffs[B+1]
static const size_t SMALL= 31342272;
static const size_t BN0S = SMALL;                // 1024
static const size_t BN1S = BN0S + 1024;          // 128
static const size_t ZCNT = 1152;                 // floats to zero (BN stats only)
static const size_t EMB  = BN1S + 128;           // 64*64 emb
static const size_t Z1C  = EMB + 4096;           // 64*256 classifier z1
static const size_t Z2C  = Z1C + 16384;          // 64*128 classifier z2

__device__ __forceinline__ float lrelu(float x){ return x > 0.f ? x : 0.2f * x; }
__device__ __forceinline__ float elu(float x){ return x > 0.f ? x : expm1f(x); }
__device__ __forceinline__ u16 fbf(float f){           // fp32 -> bf16 RNE
  unsigned u = __float_as_uint(f);
  return (u16)((u + 0x7fffu + ((u >> 16) & 1u)) >> 16);
}
__device__ __forceinline__ float blo(unsigned u){ return __uint_as_float(u << 16); }
__device__ __forceinline__ float bhi(unsigned u){ return __uint_as_float(u & 0xffff0000u); }

// ---------------- fp32 -> bf16 (n multiple of 4) ----------------
__global__ __launch_bounds__(256) void conv_bf(const float* __restrict__ src,
                                               u16* __restrict__ dst, int n4){
  int i = blockIdx.x * 256 + threadIdx.x;
  if (i < n4){
    float4 v = ((const float4*)src)[i];
    ushort4 o; o.x = fbf(v.x); o.y = fbf(v.y); o.z = fbf(v.z); o.w = fbf(v.w);
    ((ushort4*)dst)[i] = o;
  }
}

// ---------------- all 4 GAT weights: W[K][N] fp32 -> WT[N][K] bf16, one launch
__global__ __launch_bounds__(256) void conv_wt4(const float* __restrict__ W0,
    const float* __restrict__ W1, const float* __restrict__ W2,
    const float* __restrict__ W3, u16* __restrict__ O){
  int which = blockIdx.y;
  const float* W = (which == 0) ? W0 : (which == 1) ? W1 : (which == 2) ? W2 : W3;
  int K = (which < 2) ? 256 : 512;
  int N = (which < 2) ? 512 : 256;
  u16* out = O + which * 131072;
  int i = blockIdx.x * 256 + threadIdx.x;   // < 131072
  int n = i / K, k = i - n * K;
  out[i] = fbf(W[k * N + n]);
}

// ---------------- MFMA GEMM: O[M][Nc] = A[M][K] @ WT[Nc][K]^T, all bf16, fp32 acc
__global__ __launch_bounds__(256) void gemm_mfma(const u16* __restrict__ A,
    const u16* __restrict__ WTa, const u16* __restrict__ WTb,
    u16* __restrict__ Oa, u16* __restrict__ Ob, int M, int K, int Nc){
  const u16* WT = blockIdx.z ? WTb : WTa;
  u16* O = blockIdx.z ? Ob : Oa;
  __shared__ u16 As[128 * 40];   // row stride 40 u16 = 80B -> 2-way bank alias (free)
  __shared__ u16 Bs[128 * 40];
  int tid = threadIdx.x;
  int m0 = blockIdx.y * 128, n0 = blockIdx.x * 128;
  int lane = tid & 63, w = tid >> 6;
  int wr = (w >> 1) * 64, wc = (w & 1) * 64;
  int l16 = lane & 15, kq = lane >> 4;
  f32x4 acc[4][4] = {};
  int srow = tid >> 2, scol = (tid & 3) * 8;
  for (int kt = 0; kt < K; kt += 32){
    #pragma unroll
    for (int r = 0; r < 2; r++){
      int row = r * 64 + srow;
      uint4 av = make_uint4(0u, 0u, 0u, 0u);
      int gr = m0 + row;
      if (gr < M) av = *(const uint4*)&A[(size_t)gr * K + kt + scol];
      *(uint4*)&As[row * 40 + scol] = av;
      uint4 bv = *(const uint4*)&WT[(size_t)(n0 + row) * K + kt + scol];
      *(uint4*)&Bs[row * 40 + scol] = bv;
    }
    __syncthreads();
    bf16x8 af[4], bfr[4];
    #pragma unroll
    for (int i = 0; i < 4; i++){
      af[i]  = *(bf16x8*)&As[(wr + i * 16 + l16) * 40 + kq * 8];
      bfr[i] = *(bf16x8*)&Bs[(wc + i * 16 + l16) * 40 + kq * 8];
    }
    #pragma unroll
    for (int i = 0; i < 4; i++)
      #pragma unroll
      for (int j = 0; j < 4; j++)
        acc[i][j] = __builtin_amdgcn_mfma_f32_16x16x32_bf16(af[i], bfr[j], acc[i][j], 0, 0, 0);
    __syncthreads();
  }
  #pragma unroll
  for (int i = 0; i < 4; i++){
    #pragma unroll
    for (int rg = 0; rg < 4; rg++){
      int row = m0 + wr + i * 16 + kq * 4 + rg;
      if (row < M){
        #pragma unroll
        for (int j = 0; j < 4; j++){
          int col = n0 + wc + j * 16 + l16;
          O[(size_t)row * Nc + col] = fbf(acc[i][j][rg]);
        }
      }
    }
  }
}

// ---------------- CSR build ----------------
__global__ __launch_bounds__(256) void csr_hist(const int* __restrict__ ei,
                                                int* __restrict__ cursor){
  int e = blockIdx.x * 256 + threadIdx.x;
  if (e < Ee) atomicAdd(&cursor[ei[Ee + e]], 1);
}

__global__ __launch_bounds__(1024) void csr_scan(int* __restrict__ offs,
                                                 int* __restrict__ cursor){
  __shared__ int part[1024];
  int t = threadIdx.x;
  int base = t * 20;
  int loc[20];
  int s = 0;
  #pragma unroll
  for (int i = 0; i < 20; i++){
    int idx = base + i;
    int v = (idx < Nn) ? cursor[idx] : 0;
    loc[i] = s; s += v;
  }
  part[t] = s;
  __syncthreads();
  for (int off = 1; off < 1024; off <<= 1){
    int v = 0;
    if (t >= off) v = part[t - off];
    __syncthreads();
    if (t >= off) part[t] += v;
    __syncthreads();
  }
  int pre = (t == 0) ? 0 : part[t - 1];
  #pragma unroll
  for (int i = 0; i < 20; i++){
    int idx = base + i;
    if (idx < Nn){ offs[idx] = pre + loc[i]; cursor[idx] = pre + loc[i]; }
  }
  if (t == 1023) offs[Nn] = part[1023];
}

__global__ __launch_bounds__(256) void csr_fill(const int* __restrict__ ei,
    int* __restrict__ cursor, int* __restrict__ eidx){
  int e = blockIdx.x * 256 + threadIdx.x;
  if (e < Ee){
    int d = ei[Ee + e];
    int p = atomicAdd(&cursor[d], 1);
    eidx[p] = e;
  }
}

// ---------------- graph boundaries from sorted batch
__global__ __launch_bounds__(256) void graph_bounds(const int* __restrict__ batch,
                                                    int* __restrict__ goffs){
  int i = blockIdx.x * 256 + threadIdx.x;
  if (i >= Nn) return;
  int b1 = batch[i];
  int b0 = (i == 0) ? -1 : batch[i - 1];
  for (int b = b0 + 1; b <= b1; b++) goffs[b] = i;
  if (i == Nn - 1)
    for (int b = b1 + 1; b <= Bb; b++) goffs[b] = Nn;
}

// ---------------- fused layer-0: score + online-softmax + aggregate, wave/dst
// 2-edge ILP unroll: two independent gathers + score chains per iteration,
// one merged online-softmax update.
__global__ __launch_bounds__(256) void fused_l0(const u16* __restrict__ xl,
    const u16* __restrict__ xr, const float* __restrict__ ea,
    const float* __restrict__ we, const float* __restrict__ att,
    const int* __restrict__ ei, const int* __restrict__ offs,
    const int* __restrict__ eidx, float* __restrict__ out){
  int n = blockIdx.x * 4 + (threadIdx.x >> 6);
  int lane = threadIdx.x & 63;
  int s = offs[n], e = offs[n + 1];
  int c = lane << 3;            // 8 channels/lane, head = lane>>4
  uint4 ru = *(const uint4*)&xr[(size_t)n * 512 + c];
  float r0=blo(ru.x), r1=bhi(ru.x), r2=blo(ru.y), r3=bhi(ru.y),
        r4=blo(ru.z), r5=bhi(ru.z), r6=blo(ru.w), r7=bhi(ru.w);
  float4 w0 = *(const float4*)&we[c],  w1 = *(const float4*)&we[c + 4];
  float4 t0 = *(const float4*)&att[c], t1 = *(const float4*)&att[c + 4];
  float m = -INFINITY, d = 0.f;
  float a0=0.f,a1=0.f,a2=0.f,a3=0.f,a4=0.f,a5=0.f,a6=0.f,a7=0.f;
  int i = s;
  for (; i + 2 <= e; i += 2){
    int eA = eidx[i], eB = eidx[i + 1];
    int sA = ei[eA], sB = ei[eB];
    float avA = ea[eA], avB = ea[eB];
    uint4 luA = *(const uint4*)&xl[(size_t)sA * 512 + c];
    uint4 luB = *(const uint4*)&xl[(size_t)sB * 512 + c];
    float xA0=blo(luA.x), xA1=bhi(luA.x), xA2=blo(luA.y), xA3=bhi(luA.y),
          xA4=blo(luA.z), xA5=bhi(luA.z), xA6=blo(luA.w), xA7=bhi(luA.w);
    float xB0=blo(luB.x), xB1=bhi(luB.x), xB2=blo(luB.y), xB3=bhi(luB.y),
          xB4=blo(luB.z), xB5=bhi(luB.z), xB6=blo(luB.w), xB7=bhi(luB.w);
    float pA = lrelu(xA0+r0+avA*w0.x)*t0.x + lrelu(xA1+r1+avA*w0.y)*t0.y
             + lrelu(xA2+r2+avA*w0.z)*t0.z + lrelu(xA3+r3+avA*w0.w)*t0.w
             + lrelu(xA4+r4+avA*w1.x)*t1.x + lrelu(xA5+r5+avA*w1.y)*t1.y
             + lrelu(xA6+r6+avA*w1.z)*t1.z + lrelu(xA7+r7+avA*w1.w)*t1.w;
    float pB = lrelu(xB0+r0+avB*w0.x)*t0.x + lrelu(xB1+r1+avB*w0.y)*t0.y
             + lrelu(xB2+r2+avB*w0.z)*t0.z + lrelu(xB3+r3+avB*w0.w)*t0.w
             + lrelu(xB4+r4+avB*w1.x)*t1.x + lrelu(xB5+r5+avB*w1.y)*t1.y
             + lrelu(xB6+r6+avB*w1.z)*t1.z + lrelu(xB7+r7+avB*w1.w)*t1.w;
    pA += __shfl_xor(pA, 8); pB += __shfl_xor(pB, 8);
    pA += __shfl_xor(pA, 4); pB += __shfl_xor(pB, 4);
    pA += __shfl_xor(pA, 2); pB += __shfl_xor(pB, 2);
    pA += __shfl_xor(pA, 1); pB += __shfl_xor(pB, 1);
    float mn = fmaxf(m, fmaxf(pA, pB));
    float sc = expf(m - mn);
    float eeA = expf(pA - mn), eeB = expf(pB - mn);
    d = d * sc + eeA + eeB;
    a0 = a0*sc + eeA*xA0 + eeB*xB0; a1 = a1*sc + eeA*xA1 + eeB*xB1;
    a2 = a2*sc + eeA*xA2 + eeB*xB2; a3 = a3*sc + eeA*xA3 + eeB*xB3;
    a4 = a4*sc + eeA*xA4 + eeB*xB4; a5 = a5*sc + eeA*xA5 + eeB*xB5;
    a6 = a6*sc + eeA*xA6 + eeB*xB6; a7 = a7*sc + eeA*xA7 + eeB*xB7;
    m = mn;
  }
  if (i < e){
    int eA = eidx[i];
    int sA = ei[eA];
    float avA = ea[eA];
    uint4 luA = *(const uint4*)&xl[(size_t)sA * 512 + c];
    float x0=blo(luA.x), x1=bhi(luA.x), x2=blo(luA.y), x3=bhi(luA.y),
          x4=blo(luA.z), x5=bhi(luA.z), x6=blo(luA.w), x7=bhi(luA.w);
    float p = lrelu(x0+r0+avA*w0.x)*t0.x + lrelu(x1+r1+avA*w0.y)*t0.y
            + lrelu(x2+r2+avA*w0.z)*t0.z + lrelu(x3+r3+avA*w0.w)*t0.w
            + lrelu(x4+r4+avA*w1.x)*t1.x + lrelu(x5+r5+avA*w1.y)*t1.y
            + lrelu(x6+r6+avA*w1.z)*t1.z + lrelu(x7+r7+avA*w1.w)*t1.w;
    p += __shfl_xor(p, 8); p += __shfl_xor(p, 4);
    p += __shfl_xor(p, 2); p += __shfl_xor(p, 1);
    float mn = fmaxf(m, p);
    float sc = expf(m - mn);
    float ee = expf(p - mn);
    d = d * sc + ee;
    a0 = a0*sc + ee*x0; a1 = a1*sc + ee*x1;
    a2 = a2*sc + ee*x2; a3 = a3*sc + ee*x3;
    a4 = a4*sc + ee*x4; a5 = a5*sc + ee*x5;
    a6 = a6*sc + ee*x6; a7 = a7*sc + ee*x7;
  }
  float inv = 1.f / (d + 1e-16f);   // empty segment: acc=0 -> writes 0
  float4* op = (float4*)&out[(size_t)n * 512 + c];
  op[0] = make_float4(a0*inv, a1*inv, a2*inv, a3*inv);
  op[1] = make_float4(a4*inv, a5*inv, a6*inv, a7*inv);
}

// ---------------- fused layer-1: score + online-softmax + aggregate + head-mean
__global__ __launch_bounds__(256) void fused_l1(const u16* __restrict__ xl,
    const u16* __restrict__ xr, const float* __restrict__ ea,
    const float* __restrict__ we, const float* __restrict__ att,
    const int* __restrict__ ei, const int* __restrict__ offs,
    const int* __restrict__ eidx, float* __restrict__ out){
  int n = blockIdx.x * 4 + (threadIdx.x >> 6);
  int lane = threadIdx.x & 63;
  int s = offs[n], e = offs[n + 1];
  int c = lane << 2;            // 4 channels/lane; head = lane>>4
  uint2 ru = *(const uint2*)&xr[(size_t)n * 256 + c];
  float r0=blo(ru.x), r1=bhi(ru.x), r2=blo(ru.y), r3=bhi(ru.y);
  float4 w  = *(const float4*)&we[c];
  float4 tt = *(const float4*)&att[c];
  float m = -INFINITY, d = 0.f;
  float a0=0.f,a1=0.f,a2=0.f,a3=0.f;
  int i = s;
  for (; i + 2 <= e; i += 2){
    int eA = eidx[i], eB = eidx[i + 1];
    int sA = ei[eA], sB = ei[eB];
    float avA = ea[eA], avB = ea[eB];
    uint2 luA = *(const uint2*)&xl[(size_t)sA * 256 + c];
    uint2 luB = *(const uint2*)&xl[(size_t)sB * 256 + c];
    float xA0=blo(luA.x), xA1=bhi(luA.x), xA2=blo(luA.y), xA3=bhi(luA.y);
    float xB0=blo(luB.x), xB1=bhi(luB.x), xB2=blo(luB.y), xB3=bhi(luB.y);
    float pA = lrelu(xA0+r0+avA*w.x)*tt.x + lrelu(xA1+r1+avA*w.y)*tt.y
             + lrelu(xA2+r2+avA*w.z)*tt.z + lrelu(xA3+r3+avA*w.w)*tt.w;
    float pB = lrelu(xB0+r0+avB*w.x)*tt.x + lrelu(xB1+r1+avB*w.y)*tt.y
             + lrelu(xB2+r2+avB*w.z)*tt.z + lrelu(xB3+r3+avB*w.w)*tt.w;
    pA += __shfl_xor(pA, 8); pB += __shfl_xor(pB, 8);
    pA += __shfl_xor(pA, 4); pB += __shfl_xor(pB, 4);
    pA += __shfl_xor(pA, 2); pB += __shfl_xor(pB, 2);
    pA += __shfl_xor(pA, 1); pB += __shfl_xor(pB, 1);
    float mn = fmaxf(m, fmaxf(pA, pB));
    float sc = expf(m - mn);
    float eeA = expf(pA - mn), eeB = expf(pB - mn);
    d = d * sc + eeA + eeB;
    a0 = a0*sc + eeA*xA0 + eeB*xB0; a1 = a1*sc + eeA*xA1 + eeB*xB1;
    a2 = a2*sc + eeA*xA2 + eeB*xB2; a3 = a3*sc + eeA*xA3 + eeB*xB3;
    m = mn;
  }
  if (i < e){
    int eA = eidx[i];
    int sA = ei[eA];
    float avA = ea[eA];
    uint2 lu = *(const uint2*)&xl[(size_t)sA * 256 + c];
    float x0=blo(lu.x), x1=bhi(lu.x), x2=blo(lu.y), x3=bhi(lu.y);
    float p = lrelu(x0+r0+avA*w.x)*tt.x + lrelu(x1+r1+avA*w.y)*tt.y
            + lrelu(x2+r2+avA*w.z)*tt.z + lrelu(x3+r3+avA*w.w)*tt.w;
    p += __shfl_xor(p, 8); p += __shfl_xor(p, 4);
    p += __shfl_xor(p, 2); p += __shfl_xor(p, 1);
    float mn = fmaxf(m, p);
    float sc = expf(m - mn);
    float ee = expf(p - mn);
    d = d * sc + ee;
    a0 = a0*sc + ee*x0; a1 = a1*sc + ee*x1;
    a2 = a2*sc + ee*x2; a3 = a3*sc + ee*x3;
  }
  float inv = 0.25f / (d + 1e-16f);  // fold head-mean
  float v0 = a0*inv, v1 = a1*inv, v2 = a2*inv, v3 = a3*inv;
  v0 += __shfl_xor(v0, 16); v0 += __shfl_xor(v0, 32);   // sum over 4 heads
  v1 += __shfl_xor(v1, 16); v1 += __shfl_xor(v1, 32);
  v2 += __shfl_xor(v2, 16); v2 += __shfl_xor(v2, 32);
  v3 += __shfl_xor(v3, 16); v3 += __shfl_xor(v3, 32);
  if (lane < 16)
    *(float4*)&out[(size_t)n * 64 + lane * 4] = make_float4(v0, v1, v2, v3);
}

// ---------------- batchnorm reduce
__global__ void bn_reduce(const float* __restrict__ X, float* __restrict__ stats,
                          int Nr, int C, int rpb){
  int tid = threadIdx.x;
  int c = tid % C, sub = tid / C, step = blockDim.x / C;
  float s = 0.f, s2 = 0.f;
  int rend = min((int)((blockIdx.x + 1) * rpb), Nr);
  for (int r = blockIdx.x * rpb + sub; r < rend; r += step){
    float v = X[(size_t)r * C + c];
    s += v; s2 += v * v;
  }
  atomicAdd(&stats[c], s);
  atomicAdd(&stats[C + c], s2);
}

// ---------------- BN+ELU -> bf16 out (layer 0 path feeds MFMA GEMM)
__global__ __launch_bounds__(256) void bn_apply_bf(const float* __restrict__ X,
    const float* __restrict__ stats, const float* __restrict__ g,
    const float* __restrict__ b, u16* __restrict__ Xb, int total, int C, float invN){
  int idx = blockIdx.x * 256 + threadIdx.x;
  if (idx >= total) return;
  int c = idx % C;
  float mean = stats[c] * invN;
  float var = stats[C + c] * invN - mean * mean;
  float inv = rsqrtf(var + 1e-5f);
  float v = (X[idx] - mean) * inv * g[c] + b[c];
  Xb[idx] = fbf(elu(v));
}

// ---------------- BN+ELU fp32 in place (layer 1 path)
__global__ __launch_bounds__(256) void bn_apply(float* __restrict__ X,
    const float* __restrict__ stats, const float* __restrict__ g,
    const float* __restrict__ b, int total, int C, float invN){
  int idx = blockIdx.x * 256 + threadIdx.x;
  if (idx >= total) return;
  int c = idx % C;
  float mean = stats[c] * invN;
  float var = stats[C + c] * invN - mean * mean;
  float inv = rsqrtf(var + 1e-5f);
  float v = (X[idx] - mean) * inv * g[c] + b[c];
  X[idx] = elu(v);
}

// ---------------- per-graph mean pool (block per graph, no atomics)
__global__ __launch_bounds__(256) void pool_graph(const float* __restrict__ h1,
    const int* __restrict__ goffs, float* __restrict__ emb, float* __restrict__ out_emb){
  int b = blockIdx.x;
  int s = goffs[b], e = goffs[b + 1];
  int c = threadIdx.x & 63, sub = threadIdx.x >> 6;
  float acc = 0.f;
  for (int n = s + sub; n < e; n += 4) acc += h1[(size_t)n * 64 + c];
  __shared__ float red[4][64];
  red[sub][c] = acc;
  __syncthreads();
  if (sub == 0){
    float v = red[0][c] + red[1][c] + red[2][c] + red[3][c];
    v /= fmaxf((float)(e - s), 1.0f);
    emb[b * 64 + c] = v;
    out_emb[b * 64 + c] = v;
  }
}

// ---------------- classifier stage 1, parallel: 16 blocks x 16 channels.
__global__ __launch_bounds__(256) void mlp1_par(const float* __restrict__ emb,
    const float* __restrict__ W1, const float* __restrict__ b1,
    const float* __restrict__ g, const float* __restrict__ bb,
    float* __restrict__ z1){
  int t = threadIdx.x;
  int jj = t & 15, rg = t >> 4;            // rg -> rows [rg*4, rg*4+4)
  int j = blockIdx.x * 16 + jj;
  float acc[4];
  float bias = b1[j];
  #pragma unroll
  for (int r = 0; r < 4; r++) acc[r] = bias;
  for (int k = 0; k < 64; k++){
    float w = W1[k * 256 + j];
    #pragma unroll
    for (int r = 0; r < 4; r++) acc[r] += emb[(rg * 4 + r) * 64 + k] * w;
  }
  __shared__ float ssum[16][16], ssq[16][16];
  float s = 0.f, s2 = 0.f;
  #pragma unroll
  for (int r = 0; r < 4; r++){ s += acc[r]; s2 += acc[r] * acc[r]; }
  ssum[rg][jj] = s; ssq[rg][jj] = s2;
  __syncthreads();
  float S = 0.f, S2 = 0.f;
  #pragma unroll
  for (int q = 0; q < 16; q++){ S += ssum[q][jj]; S2 += ssq[q][jj]; }
  float mean = S * (1.f / 64.f);
  float var = S2 * (1.f / 64.f) - mean * mean;
  float inv = rsqrtf(var + 1e-5f);
  float sc = g[j] * inv, sh = bb[j] - mean * sc;
  #pragma unroll
  for (int r = 0; r < 4; r++)
    z1[(rg * 4 + r) * 256 + j] = elu(acc[r] * sc + sh);
}

// ---------------- classifier stage 2, parallel: 8 blocks x 16 channels, K=256
__global__ __launch_bounds__(256) void mlp2_par(const float* __restrict__ z1,
    const float* __restrict__ W2, const float* __restrict__ b2,
    const float* __restrict__ g, const float* __restrict__ bb,
    float* __restrict__ z2){
  int t = threadIdx.x;
  int jj = t & 15, rg = t >> 4;
  int j = blockIdx.x * 16 + jj;
  float acc[4];
  float bias = b2[j];
  #pragma unroll
  for (int r = 0; r < 4; r++) acc[r] = bias;
  for (int k = 0; k < 256; k++){
    float w = W2[k * 128 + j];
    #pragma unroll
    for (int r = 0; r < 4; r++) acc[r] += z1[(rg * 4 + r) * 256 + k] * w;
  }
  __shared__ float ssum[16][16], ssq[16][16];
  float s = 0.f, s2 = 0.f;
  #pragma unroll
  for (int r = 0; r < 4; r++){ s += acc[r]; s2 += acc[r] * acc[r]; }
  ssum[rg][jj] = s; ssq[rg][jj] = s2;
  __syncthreads();
  float S = 0.f, S2 = 0.f;
  #pragma unroll
  for (int q = 0; q < 16; q++){ S += ssum[q][jj]; S2 += ssq[q][jj]; }
  float mean = S * (1.f / 64.f);
  float var = S2 * (1.f / 64.f) - mean * mean;
  float inv = rsqrtf(var + 1e-5f);
  float sc = g[j] * inv, sh = bb[j] - mean * sc;
  #pragma unroll
  for (int r = 0; r < 4; r++)
    z2[(rg * 4 + r) * 128 + j] = elu(acc[r] * sc + sh);
}

// ---------------- classifier stage 3: logits
__global__ __launch_bounds__(128) void mlp3(const float* __restrict__ z2,
    const float* __restrict__ W3, const float* __restrict__ b3, float* __restrict__ out){
  int tid = threadIdx.x;
  int b = tid >> 1, o = tid & 1;
  float acc = b3[o];
  for (int k = 0; k < 128; k++) acc += z2[b * 128 + k] * W3[k * 2 + o];
  out[b * 2 + o] = acc;
}

extern "C" void kernel_launch(void* const* d_in, const int* in_sizes, int n_in,
                              void* d_out, int out_size, void* d_ws, size_t ws_size,
                              hipStream_t stream){
  const float* x      = (const float*)d_in[0];
  const int*   ei     = (const int*)d_in[1];
  const float* ea     = (const float*)d_in[2];
  const int*   batch  = (const int*)d_in[3];
  const float* g0_wl  = (const float*)d_in[4];
  const float* g0_wr  = (const float*)d_in[5];
  const float* g0_we  = (const float*)d_in[6];
  const float* g0_att = (const float*)d_in[7];
  const float* bn0_g  = (const float*)d_in[9];
  const float* bn0_b  = (const float*)d_in[10];
  const float* g1_wl  = (const float*)d_in[11];
  const float* g1_wr  = (const float*)d_in[12];
  const float* g1_we  = (const float*)d_in[13];
  const float* g1_att = (const float*)d_in[14];
  const float* bn1_g  = (const float*)d_in[16];
  const float* bn1_b  = (const float*)d_in[17];
  const float* c_w1   = (const float*)d_in[18];
  const float* c_b1   = (const float*)d_in[19];
  const float* cbn1_g = (const float*)d_in[20];
  const float* cbn1_b = (const float*)d_in[21];
  const float* c_w2   = (const float*)d_in[22];
  const float* c_b2   = (const float*)d_in[23];
  const float* cbn2_g = (const float*)d_in[24];
  const float* cbn2_b = (const float*)d_in[25];
  const float* c_w3   = (const float*)d_in[26];
  const float* c_b3   = (const float*)d_in[27];
  float* out = (float*)d_out;
  float* ws = (float*)d_ws;

  u16* xb   = (u16*)(ws + XB);
  u16* xl0b = (u16*)(ws + XL0B);
  u16* xr0b = (u16*)(ws + XR0B);
  u16* h0b  = (u16*)(ws + H0B);
  u16* wt0a = (u16*)(ws + WTS);
  u16* wt0b = wt0a + 131072;
  u16* wt1a = wt0a + 262144;
  u16* wt1b = wt0a + 393216;
  int* offs   = (int*)(ws + CSRI);
  int* cursor = offs + (Nn + 1);
  int* eidx   = cursor + Nn;
  int* goffs  = eidx + Ee;          // B+1

  hipMemsetAsync(cursor, 0, Nn * sizeof(int), stream);
  hipMemsetAsync(ws + SMALL, 0, ZCNT * sizeof(float), stream);

  // ---- conversions ----
  conv_bf<<<(Nn * 256 / 4 + 255) / 256, 256, 0, stream>>>(x, xb, Nn * 256 / 4);
  conv_wt4<<<dim3(512, 4), 256, 0, stream>>>(g0_wl, g0_wr, g1_wl, g1_wr, wt0a);

  // ---- CSR by destination + graph bounds ----
  csr_hist<<<(Ee + 255) / 256, 256, 0, stream>>>(ei, cursor);
  csr_scan<<<1, 1024, 0, stream>>>(offs, cursor);
  csr_fill<<<(Ee + 255) / 256, 256, 0, stream>>>(ei, cursor, eidx);
  graph_bounds<<<(Nn + 255) / 256, 256, 0, stream>>>(batch, goffs);

  // ---- layer 0 ----
  gemm_mfma<<<dim3(4, 157, 2), 256, 0, stream>>>(xb, wt0a, wt0b, xl0b, xr0b,
                                                 Nn, 256, 512);
  fused_l0<<<Nn / 4, 256, 0, stream>>>(xl0b, xr0b, ea, g0_we, g0_att, ei,
                                       offs, eidx, ws + OUT0);
  bn_reduce<<<200, 512, 0, stream>>>(ws + OUT0, ws + BN0S, Nn, 512, 100);
  bn_apply_bf<<<40000, 256, 0, stream>>>(ws + OUT0, ws + BN0S, bn0_g, bn0_b, h0b,
                                         Nn * 512, 512, 1.f / Nn);
  // ---- layer 1 ----
  gemm_mfma<<<dim3(2, 157, 2), 256, 0, stream>>>(h0b, wt1a, wt1b, xl0b, xr0b,
                                                 Nn, 512, 256);
  fused_l1<<<Nn / 4, 256, 0, stream>>>(xl0b, xr0b, ea, g1_we, g1_att, ei,
                                       offs, eidx, ws + OUT1);
  bn_reduce<<<50, 256, 0, stream>>>(ws + OUT1, ws + BN1S, Nn, 64, 400);
  bn_apply<<<5000, 256, 0, stream>>>(ws + OUT1, ws + BN1S, bn1_g, bn1_b,
                                     Nn * 64, 64, 1.f / Nn);
  // ---- pool + parallel classifier ----
  pool_graph<<<Bb, 256, 0, stream>>>(ws + OUT1, goffs, ws + EMB, out + 128);
  mlp1_par<<<16, 256, 0, stream>>>(ws + EMB, c_w1, c_b1, cbn1_g, cbn1_b, ws + Z1C);
  mlp2_par<<<8, 256, 0, stream>>>(ws + Z1C, c_w2, c_b2, cbn2_g, cbn2_b, ws + Z2C);
  mlp3<<<1, 128, 0, stream>>>(ws + Z2C, c_w3, c_b3, out);
}